// Round 1
// baseline (3662.086 us; speedup 1.0000x reference)
//
#include <hip/hip_runtime.h>
#include <stdint.h>

// LSTM (packed sequence) on MI355X.
// T=512, B=64, D=512, H=512. out[t,b,:] = masked h_t.
// Fused design: one cooperative kernel runs all 512 timesteps.
//   - Per step, each of 128 WGs owns a (16-batch x 16-hidden) output tile and
//     computes all 4 gates for it: preact = x_t@Wx^T + h_{t-1}@Wh^T + b.
//   - bf16 3-split MFMA (hi/lo) for ~1e-5 per-step accuracy (fp32-class).
//   - Weight fragments persistent in VGPRs (prepped by build_frags).
//   - h exchanged cross-XCD via LLC using relaxed agent-scope atomics
//     (packed bf16 hi|lo dwords), double-buffered by step parity.
//   - One custom grid barrier per step (generation counter at LLC).

#define TT 512
#define BB 64
#define DD 512
#define HH 512
#define NWG 128
#define NTHR 512

typedef short short8 __attribute__((ext_vector_type(8)));
typedef float f32x4 __attribute__((ext_vector_type(4)));

__device__ __forceinline__ uint16_t bf16_rne(float f) {
  uint32_t u = __float_as_uint(f);
  u += 0x7fffu + ((u >> 16) & 1u);
  return (uint16_t)(u >> 16);
}

__device__ __forceinline__ void split2(float f, uint16_t &hi, uint16_t &lo) {
  uint16_t h = bf16_rne(f);
  hi = h;
  lo = bf16_rne(f - __uint_as_float(((uint32_t)h) << 16));
}

__device__ __forceinline__ float sigf(float v) { return 1.0f / (1.0f + __expf(-v)); }
__device__ __forceinline__ float tanh_(float v) {
  return 1.0f - 2.0f / (__expf(2.0f * v) + 1.0f);
}

// Build MFMA B-fragment buffer from W [2048][512] (row-major, k contiguous).
// frag[nblk][ks][lane][0..3]=hi dwords, [4..7]=lo dwords.
// B-frag lane layout for mfma_f32_16x16x32_bf16: col = lane&15,
// k = ks*32 + (lane>>4)*8 + j (8 contiguous k per lane).
__global__ void build_frags(const float* __restrict__ W, uint32_t* __restrict__ frag) {
  const int tid = blockIdx.x * 256 + threadIdx.x;   // 0..131071
  const int lane = tid & 63;
  const int ks = (tid >> 6) & 15;
  const int nblk = tid >> 10;                        // 0..127
  const int col = nblk * 16 + (lane & 15);
  const int k0 = ks * 32 + ((lane >> 4) << 3);
  const float* src = W + (size_t)col * 512 + k0;
  float4 a = *(const float4*)(src);
  float4 b = *(const float4*)(src + 4);
  float v[8] = {a.x, a.y, a.z, a.w, b.x, b.y, b.z, b.w};
  uint32_t hw[4], lw[4];
#pragma unroll
  for (int j = 0; j < 4; ++j) {
    uint16_t h0, l0, h1, l1;
    split2(v[2 * j], h0, l0);
    split2(v[2 * j + 1], h1, l1);
    hw[j] = (uint32_t)h0 | ((uint32_t)h1 << 16);
    lw[j] = (uint32_t)l0 | ((uint32_t)l1 << 16);
  }
  uint4* dst = (uint4*)(frag + (size_t)tid * 8);
  dst[0] = make_uint4(hw[0], hw[1], hw[2], hw[3]);
  dst[1] = make_uint4(lw[0], lw[1], lw[2], lw[3]);
}

__device__ __forceinline__ void grid_barrier(uint32_t* bar) {
  // All cross-WG data (h_pair) was written with agent-scope atomic stores
  // (sc1 -> LLC). Drain them, then arrive.
  asm volatile("s_waitcnt vmcnt(0)" ::: "memory");
  __syncthreads();
  if (threadIdx.x == 0) {
    uint32_t* cnt = bar;
    uint32_t* gen = bar + 32;  // different cache line
    uint32_t g0 = __hip_atomic_load(gen, __ATOMIC_RELAXED, __HIP_MEMORY_SCOPE_AGENT);
    uint32_t a = __hip_atomic_fetch_add(cnt, 1u, __ATOMIC_RELAXED, __HIP_MEMORY_SCOPE_AGENT);
    if (a == NWG - 1u) {
      __hip_atomic_store(cnt, 0u, __ATOMIC_RELAXED, __HIP_MEMORY_SCOPE_AGENT);
      asm volatile("s_waitcnt vmcnt(0)" ::: "memory");  // reset visible before release
      __hip_atomic_fetch_add(gen, 1u, __ATOMIC_RELAXED, __HIP_MEMORY_SCOPE_AGENT);
    } else {
      while (__hip_atomic_load(gen, __ATOMIC_RELAXED, __HIP_MEMORY_SCOPE_AGENT) == g0) {
      }
    }
  }
  __syncthreads();
}

__global__ __launch_bounds__(NTHR, 2) void lstm_main(
    const float* __restrict__ x, const int* __restrict__ len,
    const float* __restrict__ bias, const uint32_t* __restrict__ fragWx,
    const uint32_t* __restrict__ fragWh, uint32_t* __restrict__ h_pair,
    float* __restrict__ out, uint32_t* __restrict__ bar) {
  const int tid = threadIdx.x;
  const int lane = tid & 63;
  const int wave = tid >> 6;      // 0..7
  const int gp = wave >> 1;       // gate 0..3 (i,f,c,o)
  const int kh = wave & 1;        // K half (0: k<256, 1: k>=256)
  const int bblk = blockIdx.x >> 5;   // 0..3  (16 batch rows each)
  const int jblk = blockIdx.x & 31;   // 0..31 (16 hidden cols each)
  const int b0 = bblk << 4;
  const int j0 = jblk << 4;

  // LDS: shared A tile (time-shared between h-phase and x-phase), swizzled.
  __shared__ uint16_t AH[16 * 512];   // 16 KB
  __shared__ uint16_t AL[16 * 512];   // 16 KB
  __shared__ float ex[8][16][16];     // 8 KB per-wave partial preacts
  __shared__ float c_st[16][16];
  __shared__ float h_st[16][16];
  __shared__ float bias_l[4][16];
  __shared__ int len_l[16];

  if (tid < 256) {
    c_st[tid >> 4][tid & 15] = 0.0f;
    h_st[tid >> 4][tid & 15] = 0.0f;
  }
  if (tid < 64) bias_l[tid >> 4][tid & 15] = bias[(size_t)(tid >> 4) * HH + j0 + (tid & 15)];
  if (tid < 16) len_l[tid] = len[b0 + tid];

  // Persistent B fragments: this wave's gate, this jblk, its K half.
  // 8 ksteps x (hi,lo) x 2 weights = 32 x short8 = 128 VGPR.
  short8 bxh[8], bxl[8], bhh[8], bhl[8];
  {
    const int nblk = gp * 32 + jblk;
#pragma unroll
    for (int ksl = 0; ksl < 8; ++ksl) {
      const size_t idx = ((size_t)(nblk * 16 + kh * 8 + ksl) * 64 + lane) * 8;
      uint4 vh = *(const uint4*)(fragWx + idx);
      uint4 vl = *(const uint4*)(fragWx + idx + 4);
      bxh[ksl] = __builtin_bit_cast(short8, vh);
      bxl[ksl] = __builtin_bit_cast(short8, vl);
      uint4 wh = *(const uint4*)(fragWh + idx);
      uint4 wl = *(const uint4*)(fragWh + idx + 4);
      bhh[ksl] = __builtin_bit_cast(short8, wh);
      bhl[ksl] = __builtin_bit_cast(short8, wl);
    }
  }
  __syncthreads();

  // A-frag read addressing (swizzled): row = lane&15, k-chunk = (lane>>4)*8.
  const int arow = lane & 15;
  const int achk = (lane >> 4) << 4;          // byte offset of 16B chunk in row
  const int axr = (arow & 7) << 4;            // per-row XOR swizzle
  const char* rowH = (const char*)AH + arow * 1024;
  const char* rowL = (const char*)AL + arow * 1024;

  for (int t = 0; t < TT; ++t) {
    const int rbuf = t & 1;
    const int wbuf = rbuf ^ 1;

    // --- prefetch x_t tile into registers (latency hides under h phase) ---
    float4 xp[4];
#pragma unroll
    for (int i = 0; i < 4; ++i) {
      const int flat4 = i * 2048 + tid * 4;
      const int row = flat4 >> 9;
      const int col = flat4 & 511;
      xp[i] = *(const float4*)(x + ((size_t)t * BB + b0 + row) * DD + col);
    }

    f32x4 hh = {0.f, 0.f, 0.f, 0.f}, lh = {0.f, 0.f, 0.f, 0.f}, hl = {0.f, 0.f, 0.f, 0.f};

    // --- h phase: stage h_{t-1} (LLC-coherent), then MFMA ---
    if (t > 0) {
#pragma unroll
      for (int i = 0; i < 8; ++i) {
        const int flat2 = i * 1024 + tid * 2;
        const int row = flat2 >> 9;
        const int col = flat2 & 511;
        unsigned long long v = __hip_atomic_load(
            (unsigned long long*)(h_pair + ((size_t)rbuf * BB + b0 + row) * HH + col),
            __ATOMIC_RELAXED, __HIP_MEMORY_SCOPE_AGENT);
        const uint32_t d0 = (uint32_t)v, d1 = (uint32_t)(v >> 32);
        const uint32_t hw = (d0 & 0xffffu) | (d1 << 16);
        const uint32_t lw = (d0 >> 16) | (d1 & 0xffff0000u);
        const int off = row * 1024 + ((col * 2) ^ ((row & 7) << 4));
        *(uint32_t*)((char*)AH + off) = hw;
        *(uint32_t*)((char*)AL + off) = lw;
      }
      __syncthreads();
#pragma unroll
      for (int ksl = 0; ksl < 8; ++ksl) {
        const int off = ((kh * 8 + ksl) * 64 + achk) ^ axr;
        short8 ah = *(const short8*)(rowH + off);
        short8 al = *(const short8*)(rowL + off);
        hh = __builtin_amdgcn_mfma_f32_16x16x32_bf16(ah, bhh[ksl], hh, 0, 0, 0);
        lh = __builtin_amdgcn_mfma_f32_16x16x32_bf16(al, bhh[ksl], lh, 0, 0, 0);
        hl = __builtin_amdgcn_mfma_f32_16x16x32_bf16(ah, bhl[ksl], hl, 0, 0, 0);
      }
      __syncthreads();  // done reading A tile; allow overwrite
    }

    // --- x phase: convert + stage x_t, then MFMA ---
#pragma unroll
    for (int i = 0; i < 4; ++i) {
      const int flat4 = i * 2048 + tid * 4;
      const int row = flat4 >> 9;
      const int col = flat4 & 511;
      uint16_t h0, l0, h1, l1, h2, l2, h3, l3;
      split2(xp[i].x, h0, l0);
      split2(xp[i].y, h1, l1);
      split2(xp[i].z, h2, l2);
      split2(xp[i].w, h3, l3);
      const uint32_t hw0 = (uint32_t)h0 | ((uint32_t)h1 << 16);
      const uint32_t hw1 = (uint32_t)h2 | ((uint32_t)h3 << 16);
      const uint32_t lw0 = (uint32_t)l0 | ((uint32_t)l1 << 16);
      const uint32_t lw1 = (uint32_t)l2 | ((uint32_t)l3 << 16);
      const int off = row * 1024 + ((col * 2) ^ ((row & 7) << 4));
      *(uint2*)((char*)AH + off) = make_uint2(hw0, hw1);
      *(uint2*)((char*)AL + off) = make_uint2(lw0, lw1);
    }
    __syncthreads();
#pragma unroll
    for (int ksl = 0; ksl < 8; ++ksl) {
      const int off = ((kh * 8 + ksl) * 64 + achk) ^ axr;
      short8 ah = *(const short8*)(rowH + off);
      short8 al = *(const short8*)(rowL + off);
      hh = __builtin_amdgcn_mfma_f32_16x16x32_bf16(ah, bxh[ksl], hh, 0, 0, 0);
      lh = __builtin_amdgcn_mfma_f32_16x16x32_bf16(al, bxh[ksl], lh, 0, 0, 0);
      hl = __builtin_amdgcn_mfma_f32_16x16x32_bf16(ah, bxl[ksl], hl, 0, 0, 0);
    }

    // --- exchange partial preacts ---
    {
      const int crow = (lane >> 4) << 2;   // C/D layout: row=(lane>>4)*4+r
      const int ccol = lane & 15;          //             col=lane&15
#pragma unroll
      for (int r = 0; r < 4; ++r) ex[wave][crow + r][ccol] = hh[r] + lh[r] + hl[r];
    }
    __syncthreads();

    // --- cell update (one thread per (b,j) element) ---
    if (tid < 256) {
      const int brow = tid >> 4;
      const int jc = tid & 15;
      const float p0 = ex[0][brow][jc] + ex[1][brow][jc] + bias_l[0][jc];
      const float p1 = ex[2][brow][jc] + ex[3][brow][jc] + bias_l[1][jc];
      const float p2 = ex[4][brow][jc] + ex[5][brow][jc] + bias_l[2][jc];
      const float p3 = ex[6][brow][jc] + ex[7][brow][jc] + bias_l[3][jc];
      const float ig = sigf(p0);
      const float fg = sigf(p1);
      const float cc = tanh_(p2);
      const float og = sigf(p3);
      const float co = c_st[brow][jc];
      const float ct = fg * co + ig * cc;
      const float ht = og * tanh_(ct);
      const bool m = (t < len_l[brow]);
      const float cn = m ? ct : co;
      const float hn = m ? ht : h_st[brow][jc];
      c_st[brow][jc] = cn;
      h_st[brow][jc] = hn;
      out[((size_t)t * BB + b0 + brow) * HH + j0 + jc] = m ? ht : 0.0f;
      uint16_t ph, pl;
      split2(hn, ph, pl);
      __hip_atomic_store(h_pair + ((size_t)wbuf * BB + b0 + brow) * HH + j0 + jc,
                         (uint32_t)ph | ((uint32_t)pl << 16), __ATOMIC_RELAXED,
                         __HIP_MEMORY_SCOPE_AGENT);
    }

    grid_barrier(bar);
  }
}

extern "C" void kernel_launch(void* const* d_in, const int* in_sizes, int n_in,
                              void* d_out, int out_size, void* d_ws, size_t ws_size,
                              hipStream_t stream) {
  const float* x = (const float*)d_in[0];
  const int* len = (const int*)d_in[1];       // jax default: int32
  const float* Wx = (const float*)d_in[2];    // [2048][512]
  const float* Wh = (const float*)d_in[3];    // [2048][512]
  const float* bias = (const float*)d_in[4];  // [2048]
  float* out = (float*)d_out;

  const size_t FRAG_DW = (size_t)128 * 16 * 64 * 8;  // 1M dwords = 4 MB
  uint32_t* fragWx = (uint32_t*)d_ws;
  uint32_t* fragWh = fragWx + FRAG_DW;
  uint32_t* h_pair = fragWh + FRAG_DW;               // [2][64][512] dwords
  uint32_t* bar = h_pair + 2 * BB * HH;

  hipMemsetAsync(bar, 0, 256, stream);

  build_frags<<<dim3(512), dim3(256), 0, stream>>>(Wx, fragWx);
  build_frags<<<dim3(512), dim3(256), 0, stream>>>(Wh, fragWh);

  void* args[] = {(void*)&x,      (void*)&len,    (void*)&bias, (void*)&fragWx,
                  (void*)&fragWh, (void*)&h_pair, (void*)&out,  (void*)&bar};
  hipLaunchCooperativeKernel((void*)lstm_main, dim3(NWG), dim3(NTHR), args, 0, stream);
}

// Round 2
// 2329.089 us; speedup vs baseline: 1.5723x; 1.5723x over previous
//
#include <hip/hip_runtime.h>
#include <stdint.h>

// LSTM (packed sequence) on MI355X — round 2.
// T=512, B=64, D=512, H=512. out[t,b,:] = masked h_t.
// One cooperative kernel runs all 512 timesteps.
//   - 128 WGs = 4 independent groups (one per 16-batch block) x 32 jblk.
//   - Cross-WG sync: per-producer monotonic version flags (no central barrier).
//   - x-projection GEMM for step t+1 computed in step t's tail (off the
//     serial h-recurrence path); accumulator carried in VGPRs.
//   - bf16 3-split MFMA (hi/lo) for fp32-class accuracy.
//   - Weight fragments persistent in VGPRs (prepped by build_frags).
//   - h exchanged via LLC with relaxed agent-scope atomics (packed bf16
//     hi|lo dwords), double-buffered by step parity.

#define TT 512
#define BB 64
#define DD 512
#define HH 512
#define NWG 128
#define NTHR 512

typedef short short8 __attribute__((ext_vector_type(8)));
typedef float f32x4 __attribute__((ext_vector_type(4)));

__device__ __forceinline__ uint16_t bf16_rne(float f) {
  uint32_t u = __float_as_uint(f);
  u += 0x7fffu + ((u >> 16) & 1u);
  return (uint16_t)(u >> 16);
}

__device__ __forceinline__ void split2(float f, uint16_t &hi, uint16_t &lo) {
  uint16_t h = bf16_rne(f);
  hi = h;
  lo = bf16_rne(f - __uint_as_float(((uint32_t)h) << 16));
}

__device__ __forceinline__ float sigf(float v) { return 1.0f / (1.0f + __expf(-v)); }
__device__ __forceinline__ float tanh_(float v) {
  return 1.0f - 2.0f / (__expf(2.0f * v) + 1.0f);
}

// Build MFMA B-fragment buffer from W [2048][512] (row-major, k contiguous).
// frag[nblk][ks][lane][0..3]=hi dwords, [4..7]=lo dwords.
// B-frag lane layout for mfma_f32_16x16x32_bf16: col = lane&15,
// k = ks*32 + (lane>>4)*8 + j (8 contiguous k per lane).
__global__ void build_frags(const float* __restrict__ W, uint32_t* __restrict__ frag) {
  const int tid = blockIdx.x * 256 + threadIdx.x;   // 0..131071
  const int lane = tid & 63;
  const int ks = (tid >> 6) & 15;
  const int nblk = tid >> 10;                        // 0..127
  const int col = nblk * 16 + (lane & 15);
  const int k0 = ks * 32 + ((lane >> 4) << 3);
  const float* src = W + (size_t)col * 512 + k0;
  float4 a = *(const float4*)(src);
  float4 b = *(const float4*)(src + 4);
  float v[8] = {a.x, a.y, a.z, a.w, b.x, b.y, b.z, b.w};
  uint32_t hw[4], lw[4];
#pragma unroll
  for (int j = 0; j < 4; ++j) {
    uint16_t h0, l0, h1, l1;
    split2(v[2 * j], h0, l0);
    split2(v[2 * j + 1], h1, l1);
    hw[j] = (uint32_t)h0 | ((uint32_t)h1 << 16);
    lw[j] = (uint32_t)l0 | ((uint32_t)l1 << 16);
  }
  uint4* dst = (uint4*)(frag + (size_t)tid * 8);
  dst[0] = make_uint4(hw[0], hw[1], hw[2], hw[3]);
  dst[1] = make_uint4(lw[0], lw[1], lw[2], lw[3]);
}

__global__ __launch_bounds__(NTHR, 2) void lstm_main(
    const float* __restrict__ x, const int* __restrict__ len,
    const float* __restrict__ bias, const uint32_t* __restrict__ fragWx,
    const uint32_t* __restrict__ fragWh, uint32_t* __restrict__ h_pair,
    float* __restrict__ out, uint32_t* __restrict__ flags) {
  const int tid = threadIdx.x;
  const int lane = tid & 63;
  const int wave = tid >> 6;      // 0..7
  const int gp = wave >> 1;       // gate 0..3 (i,f,c,o)
  const int kh = wave & 1;        // K half (0: k<256, 1: k>=256)
  const int bblk = blockIdx.x & 3;    // group id: spreads each group over 2 XCDs
  const int jblk = blockIdx.x >> 2;   // 0..31 (16 hidden cols each)
  const int b0 = bblk << 4;
  const int j0 = jblk << 4;
  uint32_t* gflags = flags + bblk * 64;   // 32 dwords used, 256B-separated lines

  // LDS: shared A tile (time-shared between x and h phases), swizzled.
  __shared__ uint16_t AH[16 * 512];   // 16 KB
  __shared__ uint16_t AL[16 * 512];   // 16 KB
  __shared__ float ex[8][16][16];     // 8 KB per-wave partial preacts
  __shared__ float c_st[16][16];
  __shared__ float h_st[16][16];
  __shared__ float bias_l[4][16];
  __shared__ int len_l[16];

  if (tid < 256) {
    c_st[tid >> 4][tid & 15] = 0.0f;
    h_st[tid >> 4][tid & 15] = 0.0f;
  }
  if (tid < 64) bias_l[tid >> 4][tid & 15] = bias[(size_t)(tid >> 4) * HH + j0 + (tid & 15)];
  if (tid < 16) len_l[tid] = len[b0 + tid];

  // Persistent B fragments: this wave's gate, this jblk, its K half.
  short8 bxh[8], bxl[8], bhh[8], bhl[8];
  {
    const int nblk = gp * 32 + jblk;
#pragma unroll
    for (int ksl = 0; ksl < 8; ++ksl) {
      const size_t idx = ((size_t)(nblk * 16 + kh * 8 + ksl) * 64 + lane) * 8;
      uint4 vh = *(const uint4*)(fragWx + idx);
      uint4 vl = *(const uint4*)(fragWx + idx + 4);
      bxh[ksl] = __builtin_bit_cast(short8, vh);
      bxl[ksl] = __builtin_bit_cast(short8, vl);
      uint4 wh = *(const uint4*)(fragWh + idx);
      uint4 wl = *(const uint4*)(fragWh + idx + 4);
      bhh[ksl] = __builtin_bit_cast(short8, wh);
      bhl[ksl] = __builtin_bit_cast(short8, wl);
    }
  }

  // A-frag read addressing (swizzled): row = lane&15, k-chunk = (lane>>4)*8.
  const int arow = lane & 15;
  const int achk = (lane >> 4) << 4;          // byte offset of 16B chunk in row
  const int axr = (arow & 7) << 4;            // per-row XOR swizzle
  const char* rowH = (const char*)AH + arow * 1024;
  const char* rowL = (const char*)AL + arow * 1024;

  // ---- helpers as macros over local state ----
  f32x4 hh = {0.f, 0.f, 0.f, 0.f}, lh = {0.f, 0.f, 0.f, 0.f}, hl = {0.f, 0.f, 0.f, 0.f};
  float4 xp[4];

#define LOAD_XP(tt)                                                            \
  _Pragma("unroll") for (int i = 0; i < 4; ++i) {                              \
    const int flat4 = i * 2048 + tid * 4;                                      \
    const int row = flat4 >> 9;                                                \
    const int col = flat4 & 511;                                               \
    xp[i] = *(const float4*)(x + ((size_t)(tt) * BB + b0 + row) * DD + col);   \
  }

#define STAGE_XP()                                                             \
  _Pragma("unroll") for (int i = 0; i < 4; ++i) {                              \
    const int flat4 = i * 2048 + tid * 4;                                      \
    const int row = flat4 >> 9;                                                \
    const int col = flat4 & 511;                                               \
    uint16_t h0, l0, h1, l1, h2, l2, h3, l3;                                   \
    split2(xp[i].x, h0, l0);                                                   \
    split2(xp[i].y, h1, l1);                                                   \
    split2(xp[i].z, h2, l2);                                                   \
    split2(xp[i].w, h3, l3);                                                   \
    const uint32_t hw0 = (uint32_t)h0 | ((uint32_t)h1 << 16);                  \
    const uint32_t hw1 = (uint32_t)h2 | ((uint32_t)h3 << 16);                  \
    const uint32_t lw0 = (uint32_t)l0 | ((uint32_t)l1 << 16);                  \
    const uint32_t lw1 = (uint32_t)l2 | ((uint32_t)l3 << 16);                  \
    const int off = row * 1024 + ((col * 2) ^ ((row & 7) << 4));               \
    *(uint2*)((char*)AH + off) = make_uint2(hw0, hw1);                         \
    *(uint2*)((char*)AL + off) = make_uint2(lw0, lw1);                         \
  }

#define X_MFMA()                                                               \
  hh = (f32x4){0.f, 0.f, 0.f, 0.f};                                           \
  lh = (f32x4){0.f, 0.f, 0.f, 0.f};                                           \
  hl = (f32x4){0.f, 0.f, 0.f, 0.f};                                           \
  _Pragma("unroll") for (int ksl = 0; ksl < 8; ++ksl) {                        \
    const int off = ((kh * 8 + ksl) * 64 + achk) ^ axr;                        \
    short8 ah = *(const short8*)(rowH + off);                                  \
    short8 al = *(const short8*)(rowL + off);                                  \
    hh = __builtin_amdgcn_mfma_f32_16x16x32_bf16(ah, bxh[ksl], hh, 0, 0, 0);   \
    lh = __builtin_amdgcn_mfma_f32_16x16x32_bf16(al, bxh[ksl], lh, 0, 0, 0);   \
    hl = __builtin_amdgcn_mfma_f32_16x16x32_bf16(ah, bxl[ksl], hl, 0, 0, 0);   \
  }

  // ---- prologue: xacc for t=0, prefetch x_1 ----
  LOAD_XP(0);
  __syncthreads();   // bias_l/len_l ready; tile free
  STAGE_XP();
  __syncthreads();
  X_MFMA();
  LOAD_XP(1);

  for (int t = 0; t < TT; ++t) {
    const int rbuf = t & 1;
    const int wbuf = rbuf ^ 1;

    // --- wait for h_{t-1}, then h phase ---
    if (t > 0) {
      {
        uint32_t v;
        do {
          v = __hip_atomic_load(gflags + (lane & 31), __ATOMIC_RELAXED,
                                __HIP_MEMORY_SCOPE_AGENT);
        } while (__ballot(v < (uint32_t)t) != 0ull);
      }
      __syncthreads();   // join waves; x-MFMA of prev tail done -> tile free
#pragma unroll
      for (int i = 0; i < 8; ++i) {
        const int flat2 = i * 1024 + tid * 2;
        const int row = flat2 >> 9;
        const int col = flat2 & 511;
        unsigned long long v = __hip_atomic_load(
            (unsigned long long*)(h_pair + ((size_t)rbuf * BB + b0 + row) * HH + col),
            __ATOMIC_RELAXED, __HIP_MEMORY_SCOPE_AGENT);
        const uint32_t d0 = (uint32_t)v, d1 = (uint32_t)(v >> 32);
        const uint32_t hw = (d0 & 0xffffu) | (d1 << 16);
        const uint32_t lw = (d0 >> 16) | (d1 & 0xffff0000u);
        const int off = row * 1024 + ((col * 2) ^ ((row & 7) << 4));
        *(uint32_t*)((char*)AH + off) = hw;
        *(uint32_t*)((char*)AL + off) = lw;
      }
      __syncthreads();
#pragma unroll
      for (int ksl = 0; ksl < 8; ++ksl) {
        const int off = ((kh * 8 + ksl) * 64 + achk) ^ axr;
        short8 ah = *(const short8*)(rowH + off);
        short8 al = *(const short8*)(rowL + off);
        hh = __builtin_amdgcn_mfma_f32_16x16x32_bf16(ah, bhh[ksl], hh, 0, 0, 0);
        lh = __builtin_amdgcn_mfma_f32_16x16x32_bf16(al, bhh[ksl], lh, 0, 0, 0);
        hl = __builtin_amdgcn_mfma_f32_16x16x32_bf16(ah, bhl[ksl], hl, 0, 0, 0);
      }
    }

    // --- exchange partial preacts ---
    {
      const int crow = (lane >> 4) << 2;   // C/D layout: row=(lane>>4)*4+r
      const int ccol = lane & 15;
#pragma unroll
      for (int r = 0; r < 4; ++r) ex[wave][crow + r][ccol] = hh[r] + lh[r] + hl[r];
    }
    __syncthreads();   // S1: ex ready; h-MFMA tile reads done -> tile free

    // --- cell update (waves 0-3) overlapped with x_{t+1} staging (all) ---
    if (tid < 256) {
      const int brow = tid >> 4;
      const int jc = tid & 15;
      const float p0 = ex[0][brow][jc] + ex[1][brow][jc] + bias_l[0][jc];
      const float p1 = ex[2][brow][jc] + ex[3][brow][jc] + bias_l[1][jc];
      const float p2 = ex[4][brow][jc] + ex[5][brow][jc] + bias_l[2][jc];
      const float p3 = ex[6][brow][jc] + ex[7][brow][jc] + bias_l[3][jc];
      const float ig = sigf(p0);
      const float fg = sigf(p1);
      const float cc = tanh_(p2);
      const float og = sigf(p3);
      const float co = c_st[brow][jc];
      const float ct = fg * co + ig * cc;
      const float ht = og * tanh_(ct);
      const bool m = (t < len_l[brow]);
      const float cn = m ? ct : co;
      const float hn = m ? ht : h_st[brow][jc];
      c_st[brow][jc] = cn;
      h_st[brow][jc] = hn;
      out[((size_t)t * BB + b0 + brow) * HH + j0 + jc] = m ? ht : 0.0f;
      uint16_t ph, pl;
      split2(hn, ph, pl);
      __hip_atomic_store(h_pair + ((size_t)wbuf * BB + b0 + brow) * HH + j0 + jc,
                         (uint32_t)ph | ((uint32_t)pl << 16), __ATOMIC_RELAXED,
                         __HIP_MEMORY_SCOPE_AGENT);
    }

    if (t + 1 < TT) {
      STAGE_XP();        // stage x_{t+1} (tile free since S1)
      __syncthreads();   // S2: drains h stores (vmcnt) + stage writes
      if (tid == 0)
        __hip_atomic_store(gflags + jblk, (uint32_t)(t + 1), __ATOMIC_RELAXED,
                           __HIP_MEMORY_SCOPE_AGENT);
      X_MFMA();          // xacc for t+1 — off the critical path
      LOAD_XP(min(t + 2, TT - 1));
    }
  }
}

extern "C" void kernel_launch(void* const* d_in, const int* in_sizes, int n_in,
                              void* d_out, int out_size, void* d_ws, size_t ws_size,
                              hipStream_t stream) {
  const float* x = (const float*)d_in[0];
  const int* len = (const int*)d_in[1];
  const float* Wx = (const float*)d_in[2];    // [2048][512]
  const float* Wh = (const float*)d_in[3];    // [2048][512]
  const float* bias = (const float*)d_in[4];  // [2048]
  float* out = (float*)d_out;

  const size_t FRAG_DW = (size_t)128 * 16 * 64 * 8;  // 1M dwords = 4 MB
  uint32_t* fragWx = (uint32_t*)d_ws;
  uint32_t* fragWh = fragWx + FRAG_DW;
  uint32_t* h_pair = fragWh + FRAG_DW;               // [2][64][512] dwords
  uint32_t* flags = h_pair + 2 * BB * HH;            // 4 groups x 64 dwords

  hipMemsetAsync(flags, 0, 1024, stream);

  build_frags<<<dim3(512), dim3(256), 0, stream>>>(Wx, fragWx);
  build_frags<<<dim3(512), dim3(256), 0, stream>>>(Wh, fragWh);

  void* args[] = {(void*)&x,      (void*)&len,    (void*)&bias, (void*)&fragWx,
                  (void*)&fragWh, (void*)&h_pair, (void*)&out,  (void*)&flags};
  hipLaunchCooperativeKernel((void*)lstm_main, dim3(NWG), dim3(NTHR), args, 0, stream);
}

// Round 4
// 1445.313 us; speedup vs baseline: 2.5338x; 1.6115x over previous
//
#include <hip/hip_runtime.h>
#include <stdint.h>

// LSTM (packed sequence) on MI355X — round 4.
// T=512, B=64, D=512, H=512. out[t,b,:] = masked h_t.
// 256 WGs = 8 groups (8 batch rows) x 32 jblk (16 hidden cols).
// Cross-WG h exchange: SELF-DESCRIBING TAGGED DATA at LLC (agent scope).
//   |h| <= 1.0 strictly => bit14 of both bf16 halves of the packed
//   (hi,lo) dword is always 0 -> carries a 2-bit step tag ((t>>1)&3).
//   Consumers poll the data dwords directly (no flags, no store drains,
//   no release/acquire): each dword is independently valid.
//   Buffers double-buffered by step parity; tag disambiguates reuse and
//   the 0xFF init pattern. Producer lag <= 1 step (poll joins whole WG)
//   makes 4-step tag aliasing impossible.
//   - bf16 3-split MFMA (hi/lo), fp32-class accuracy (proven R1-R2).
//   - Weight fragments persistent in VGPRs (build_frags).
//   - x-projection GEMM for t+1 in step t's tail (off the serial path).

#define TT 512
#define BB 64
#define DD 512
#define HH 512
#define NWG 256
#define NTHR 512
#define GR 8   // batch rows per group

typedef short short8 __attribute__((ext_vector_type(8)));
typedef float f32x4 __attribute__((ext_vector_type(4)));

__device__ __forceinline__ uint16_t bf16_rne(float f) {
  uint32_t u = __float_as_uint(f);
  u += 0x7fffu + ((u >> 16) & 1u);
  return (uint16_t)(u >> 16);
}

__device__ __forceinline__ void split2(float f, uint16_t &hi, uint16_t &lo) {
  uint16_t h = bf16_rne(f);
  hi = h;
  lo = bf16_rne(f - __uint_as_float(((uint32_t)h) << 16));
}

__device__ __forceinline__ float sigf(float v) { return 1.0f / (1.0f + __expf(-v)); }
__device__ __forceinline__ float tanh_(float v) {
  return 1.0f - 2.0f / (__expf(2.0f * v) + 1.0f);
}

// Build MFMA B-fragment buffer from W [2048][512] (row-major, k contiguous).
// B-frag lane layout for mfma_f32_16x16x32_bf16: col = lane&15,
// k = ks*32 + (lane>>4)*8 + j (8 contiguous k per lane).
__global__ void build_frags(const float* __restrict__ W, uint32_t* __restrict__ frag) {
  const int tid = blockIdx.x * 256 + threadIdx.x;   // 0..131071
  const int lane = tid & 63;
  const int ks = (tid >> 6) & 15;
  const int nblk = tid >> 10;                        // 0..127
  const int col = nblk * 16 + (lane & 15);
  const int k0 = ks * 32 + ((lane >> 4) << 3);
  const float* src = W + (size_t)col * 512 + k0;
  float4 a = *(const float4*)(src);
  float4 b = *(const float4*)(src + 4);
  float v[8] = {a.x, a.y, a.z, a.w, b.x, b.y, b.z, b.w};
  uint32_t hw[4], lw[4];
#pragma unroll
  for (int j = 0; j < 4; ++j) {
    uint16_t h0, l0, h1, l1;
    split2(v[2 * j], h0, l0);
    split2(v[2 * j + 1], h1, l1);
    hw[j] = (uint32_t)h0 | ((uint32_t)h1 << 16);
    lw[j] = (uint32_t)l0 | ((uint32_t)l1 << 16);
  }
  uint4* dst = (uint4*)(frag + (size_t)tid * 8);
  dst[0] = make_uint4(hw[0], hw[1], hw[2], hw[3]);
  dst[1] = make_uint4(lw[0], lw[1], lw[2], lw[3]);
}

__global__ __launch_bounds__(NTHR, 2) void lstm_main(
    const float* __restrict__ x, const int* __restrict__ len,
    const float* __restrict__ bias, const uint32_t* __restrict__ fragWx,
    const uint32_t* __restrict__ fragWh, uint32_t* __restrict__ h_pair,
    float* __restrict__ out) {
  const int tid = threadIdx.x;
  const int lane = tid & 63;
  const int wave = tid >> 6;      // 0..7
  const int gp = wave >> 1;       // gate 0..3 (i,f,c,o)
  const int kh = wave & 1;        // K half
  const int group = blockIdx.x & 7;
  const int jblk = blockIdx.x >> 3;   // 0..31
  const int b0 = group * GR;
  const int j0 = jblk << 4;
  uint32_t* hbase = h_pair + (size_t)group * 2 * (GR * HH);

  __shared__ uint16_t AH[GR * 512];   // 8 KB
  __shared__ uint16_t AL[GR * 512];   // 8 KB
  __shared__ float ex[8][GR][16];     // 4 KB
  __shared__ float c_st[GR][16];
  __shared__ float h_st[GR][16];
  __shared__ float bias_l[4][16];
  __shared__ int len_l[GR];

  if (tid < GR * 16) {
    c_st[tid >> 4][tid & 15] = 0.0f;
    h_st[tid >> 4][tid & 15] = 0.0f;
  }
  if (tid < 64) bias_l[tid >> 4][tid & 15] = bias[(size_t)(tid >> 4) * HH + j0 + (tid & 15)];
  if (tid < GR) len_l[tid] = len[b0 + tid];

  // Persistent B fragments: this wave's gate, this jblk, its K half.
  short8 bxh[8], bxl[8], bhh[8], bhl[8];
  {
    const int nblk = gp * 32 + jblk;
#pragma unroll
    for (int ksl = 0; ksl < 8; ++ksl) {
      const size_t idx = ((size_t)(nblk * 16 + kh * 8 + ksl) * 64 + lane) * 8;
      uint4 vh = *(const uint4*)(fragWx + idx);
      uint4 vl = *(const uint4*)(fragWx + idx + 4);
      bxh[ksl] = __builtin_bit_cast(short8, vh);
      bxl[ksl] = __builtin_bit_cast(short8, vl);
      uint4 wh = *(const uint4*)(fragWh + idx);
      uint4 wl = *(const uint4*)(fragWh + idx + 4);
      bhh[ksl] = __builtin_bit_cast(short8, wh);
      bhl[ksl] = __builtin_bit_cast(short8, wl);
    }
  }

  // A-frag addressing: row = (lane&7) (rows 8-15 of the MFMA M dim duplicate
  // 0-7; their C rows are discarded). 16B chunk = (lane>>4)*16, XOR swz row<<4.
  const int arow = lane & 7;
  const int achk = (lane >> 4) << 4;
  const int axr = arow << 4;
  const char* rowH = (const char*)AH + arow * 1024;
  const char* rowL = (const char*)AL + arow * 1024;

  f32x4 hh = {0.f, 0.f, 0.f, 0.f}, lh = {0.f, 0.f, 0.f, 0.f}, hl = {0.f, 0.f, 0.f, 0.f};
  float4 xp[2];

#define LOAD_XP(tt)                                                            \
  _Pragma("unroll") for (int i = 0; i < 2; ++i) {                              \
    const int flat4 = i * 2048 + tid * 4;                                      \
    const int row = flat4 >> 9;                                                \
    const int col = flat4 & 511;                                               \
    xp[i] = *(const float4*)(x + ((size_t)(tt) * BB + b0 + row) * DD + col);   \
  }

#define STAGE_XP()                                                             \
  _Pragma("unroll") for (int i = 0; i < 2; ++i) {                              \
    const int flat4 = i * 2048 + tid * 4;                                      \
    const int row = flat4 >> 9;                                                \
    const int col = flat4 & 511;                                               \
    uint16_t h0, l0, h1, l1, h2, l2, h3, l3;                                   \
    split2(xp[i].x, h0, l0);                                                   \
    split2(xp[i].y, h1, l1);                                                   \
    split2(xp[i].z, h2, l2);                                                   \
    split2(xp[i].w, h3, l3);                                                   \
    const uint32_t hw0 = (uint32_t)h0 | ((uint32_t)h1 << 16);                  \
    const uint32_t hw1 = (uint32_t)h2 | ((uint32_t)h3 << 16);                  \
    const uint32_t lw0 = (uint32_t)l0 | ((uint32_t)l1 << 16);                  \
    const uint32_t lw1 = (uint32_t)l2 | ((uint32_t)l3 << 16);                  \
    const int off = row * 1024 + ((col * 2) ^ (row << 4));                     \
    *(uint2*)((char*)AH + off) = make_uint2(hw0, hw1);                         \
    *(uint2*)((char*)AL + off) = make_uint2(lw0, lw1);                         \
  }

#define X_MFMA()                                                               \
  hh = (f32x4){0.f, 0.f, 0.f, 0.f};                                           \
  lh = (f32x4){0.f, 0.f, 0.f, 0.f};                                           \
  hl = (f32x4){0.f, 0.f, 0.f, 0.f};                                           \
  _Pragma("unroll") for (int ksl = 0; ksl < 8; ++ksl) {                        \
    const int off = ((kh * 8 + ksl) * 64 + achk) ^ axr;                        \
    short8 ah = *(const short8*)(rowH + off);                                  \
    short8 al = *(const short8*)(rowL + off);                                  \
    hh = __builtin_amdgcn_mfma_f32_16x16x32_bf16(ah, bxh[ksl], hh, 0, 0, 0);   \
    lh = __builtin_amdgcn_mfma_f32_16x16x32_bf16(al, bxh[ksl], lh, 0, 0, 0);   \
    hl = __builtin_amdgcn_mfma_f32_16x16x32_bf16(ah, bxl[ksl], hl, 0, 0, 0);   \
  }

  // ---- prologue: xacc for t=0, prefetch x_1 ----
  LOAD_XP(0);
  __syncthreads();
  STAGE_XP();
  __syncthreads();
  X_MFMA();
  LOAD_XP(1);

  for (int t = 0; t < TT; ++t) {
    const int rbuf = t & 1;
    const int wbuf = rbuf ^ 1;

    if (t > 0) {
      // --- poll tagged h_{t-1} data directly (this thread's 8 dwords) ---
      const uint32_t tagp = (((uint32_t)(t - 1)) >> 1) & 3u;
      const uint32_t EXd = ((tagp & 1u) << 14) | ((tagp >> 1) << 30);
      const uint64_t EX2 = ((uint64_t)EXd << 32) | EXd;
      const uint64_t MK2 = 0x4000400040004000ull;
      const unsigned long long* pb =
          (const unsigned long long*)(hbase + (size_t)rbuf * (GR * HH)) +
          (size_t)tid * 4;
      uint64_t w0, w1, w2, w3;
      for (;;) {
        w0 = __hip_atomic_load(pb + 0, __ATOMIC_RELAXED, __HIP_MEMORY_SCOPE_AGENT);
        w1 = __hip_atomic_load(pb + 1, __ATOMIC_RELAXED, __HIP_MEMORY_SCOPE_AGENT);
        w2 = __hip_atomic_load(pb + 2, __ATOMIC_RELAXED, __HIP_MEMORY_SCOPE_AGENT);
        w3 = __hip_atomic_load(pb + 3, __ATOMIC_RELAXED, __HIP_MEMORY_SCOPE_AGENT);
        const uint64_t bad =
            (((w0 ^ EX2) | (w1 ^ EX2) | (w2 ^ EX2) | (w3 ^ EX2)) & MK2);
        if (bad == 0ull) break;
      }
      __syncthreads();   // all waves have their data; prev tail X_MFMA done

      // --- clear tags, pack, store to LDS tile (swizzled) ---
      {
        const uint32_t CM = ~0x40004000u;
        uint32_t d0 = (uint32_t)w0 & CM, d1 = (uint32_t)(w0 >> 32) & CM;
        uint32_t d2 = (uint32_t)w1 & CM, d3 = (uint32_t)(w1 >> 32) & CM;
        uint32_t d4 = (uint32_t)w2 & CM, d5 = (uint32_t)(w2 >> 32) & CM;
        uint32_t d6 = (uint32_t)w3 & CM, d7 = (uint32_t)(w3 >> 32) & CM;
        const uint32_t hi0 = (d0 & 0xFFFFu) | (d1 << 16);
        const uint32_t lo0 = (d0 >> 16) | (d1 & 0xFFFF0000u);
        const uint32_t hi1 = (d2 & 0xFFFFu) | (d3 << 16);
        const uint32_t lo1 = (d2 >> 16) | (d3 & 0xFFFF0000u);
        const uint32_t hi2 = (d4 & 0xFFFFu) | (d5 << 16);
        const uint32_t lo2 = (d4 >> 16) | (d5 & 0xFFFF0000u);
        const uint32_t hi3 = (d6 & 0xFFFFu) | (d7 << 16);
        const uint32_t lo3 = (d6 >> 16) | (d7 & 0xFFFF0000u);
        // thread owns dwords [tid*8, tid*8+8): row = tid>>6 = wave,
        // byte col = lane*16; swizzle XOR (row<<4).
        const int woff = wave * 1024 + ((lane * 16) ^ (wave << 4));
        *(uint4*)((char*)AH + woff) = make_uint4(hi0, hi1, hi2, hi3);
        *(uint4*)((char*)AL + woff) = make_uint4(lo0, lo1, lo2, lo3);
      }
      __syncthreads();

      // --- h MFMA ---
#pragma unroll
      for (int ksl = 0; ksl < 8; ++ksl) {
        const int off = ((kh * 8 + ksl) * 64 + achk) ^ axr;
        short8 ah = *(const short8*)(rowH + off);
        short8 al = *(const short8*)(rowL + off);
        hh = __builtin_amdgcn_mfma_f32_16x16x32_bf16(ah, bhh[ksl], hh, 0, 0, 0);
        lh = __builtin_amdgcn_mfma_f32_16x16x32_bf16(al, bhh[ksl], lh, 0, 0, 0);
        hl = __builtin_amdgcn_mfma_f32_16x16x32_bf16(ah, bhl[ksl], hl, 0, 0, 0);
      }
    }

    // --- exchange partial preacts (C rows 0-7 only) ---
    {
      const int crow = (lane >> 4) << 2;
      const int ccol = lane & 15;
      if (crow < GR) {
#pragma unroll
        for (int r = 0; r < 4; ++r) ex[wave][crow + r][ccol] = hh[r] + lh[r] + hl[r];
      }
    }
    __syncthreads();   // S1: ex ready; tile free

    // --- cell update (8x16 = 128 threads); tagged h store fire-and-forget ---
    if (tid < GR * 16) {
      const int brow = tid >> 4;
      const int jc = tid & 15;
      const float p0 = ex[0][brow][jc] + ex[1][brow][jc] + bias_l[0][jc];
      const float p1 = ex[2][brow][jc] + ex[3][brow][jc] + bias_l[1][jc];
      const float p2 = ex[4][brow][jc] + ex[5][brow][jc] + bias_l[2][jc];
      const float p3 = ex[6][brow][jc] + ex[7][brow][jc] + bias_l[3][jc];
      const float ig = sigf(p0);
      const float fg = sigf(p1);
      const float cc = tanh_(p2);
      const float og = sigf(p3);
      const float co = c_st[brow][jc];
      const float ct = fg * co + ig * cc;
      const float ht = og * tanh_(ct);
      const bool m = (t < len_l[brow]);
      const float cn = m ? ct : co;
      const float hn = m ? ht : h_st[brow][jc];
      c_st[brow][jc] = cn;
      h_st[brow][jc] = hn;
      out[((size_t)t * BB + b0 + brow) * HH + j0 + jc] = m ? ht : 0.0f;
      uint16_t ph, pl;
      split2(hn, ph, pl);   // |hn| <= 1.0 -> bit14 of ph and pl are 0
      const uint32_t tagw = (((uint32_t)t) >> 1) & 3u;
      const uint32_t TB = ((tagw & 1u) << 14) | ((tagw >> 1) << 30);
      const uint32_t hv = ((uint32_t)ph | ((uint32_t)pl << 16)) | TB;
      __hip_atomic_store(hbase + (size_t)wbuf * (GR * HH) + brow * HH + j0 + jc,
                         hv, __ATOMIC_RELAXED, __HIP_MEMORY_SCOPE_AGENT);
    }

    if (t + 1 < TT) {
      STAGE_XP();        // stage x_{t+1}
      __syncthreads();   // S2
      X_MFMA();          // xacc for t+1 — off the serial h path
      LOAD_XP(min(t + 2, TT - 1));
    }
  }
}

extern "C" void kernel_launch(void* const* d_in, const int* in_sizes, int n_in,
                              void* d_out, int out_size, void* d_ws, size_t ws_size,
                              hipStream_t stream) {
  const float* x = (const float*)d_in[0];
  const int* len = (const int*)d_in[1];
  const float* Wx = (const float*)d_in[2];    // [2048][512]
  const float* Wh = (const float*)d_in[3];    // [2048][512]
  const float* bias = (const float*)d_in[4];  // [2048]
  float* out = (float*)d_out;

  const size_t FRAG_DW = (size_t)128 * 16 * 64 * 8;  // 1M dwords = 4 MB
  uint32_t* fragWx = (uint32_t*)d_ws;
  uint32_t* fragWh = fragWx + FRAG_DW;
  uint32_t* h_pair = fragWh + FRAG_DW;               // 8 groups x 2 x (8*512) dwords

  // 0xFF pattern -> tag bits = 3 in every dword; never matches the first
  // expected tags (0,0,1,1,2,2) and overwritten >=2x before tag 3 recurs.
  hipMemsetAsync(h_pair, 0xFF, (size_t)8 * 2 * GR * HH * 4, stream);

  build_frags<<<dim3(512), dim3(256), 0, stream>>>(Wx, fragWx);
  build_frags<<<dim3(512), dim3(256), 0, stream>>>(Wh, fragWh);

  void* args[] = {(void*)&x,      (void*)&len,    (void*)&bias, (void*)&fragWx,
                  (void*)&fragWh, (void*)&h_pair, (void*)&out};
  hipLaunchCooperativeKernel((void*)lstm_main, dim3(NWG), dim3(NTHR), args, 0, stream);
}